// Round 6
// baseline (585.888 us; speedup 1.0000x reference)
//
#include <hip/hip_runtime.h>
#include <hip/hip_bf16.h>
#include <stdint.h>

typedef __bf16 bf16_t;
typedef bf16_t bf16x8 __attribute__((ext_vector_type(8)));
typedef float f32x4 __attribute__((ext_vector_type(4)));

#define NN 10000
#define G 512          // persistent blocks (2 per CU)
#define GT (G * 256)   // total threads
#define GW (G * 4)     // total waves

__device__ __forceinline__ float b2f(unsigned short u) {
  union { unsigned int i; float f; } c; c.i = ((unsigned int)u) << 16; return c.f;
}
__device__ __forceinline__ unsigned short f2b(float f) {
  union { float f; unsigned int i; } c; c.f = f;
  unsigned int x = c.i;
  x += 0x7FFFu + ((x >> 16) & 1u);
  return (unsigned short)(x >> 16);
}

__device__ __forceinline__ void load_lds16(const void* g, void* l) {
  __builtin_amdgcn_global_load_lds(
      (const __attribute__((address_space(1))) unsigned int*)g,
      (__attribute__((address_space(3))) unsigned int*)l, 16, 0, 0);
}

union SMem {
  struct { unsigned short As[2][128 * 32]; unsigned short Bs[2][128 * 32]; } g; // 32 KB
  float tile[64][65];   // wtrans (16.6 KB)
  int partial[256];     // scan
};

// device-scope monotonic barrier: all G blocks rendezvous; acquire-side inv
// covers each proceeding CU's L1 + its XCD's L2.
__device__ __forceinline__ void gbar(int* bar, int target) {
  __syncthreads();   // drains vmcnt/lgkm for whole block before t0 releases
  if (threadIdx.x == 0) {
    __hip_atomic_fetch_add(bar, 1, __ATOMIC_RELEASE, __HIP_MEMORY_SCOPE_AGENT);
    int spins = 0;
    while (__hip_atomic_load(bar, __ATOMIC_RELAXED, __HIP_MEMORY_SCOPE_AGENT) < target) {
      __builtin_amdgcn_s_sleep(2);
      if (++spins > 100000000) break;   // bailout: wrong answer beats a hung GPU
    }
    (void)__hip_atomic_load(bar, __ATOMIC_ACQUIRE, __HIP_MEMORY_SCOPE_AGENT);
  }
  __syncthreads();
}

// ---- GEMM tile: C[128 x 128] @ (tm,tn); A,Bt bf16 [.][512]; dbuf K-loop ----
__device__ __forceinline__ f32x4 mfma16(bf16x8 a, bf16x8 b, f32x4 c) {
  return __builtin_amdgcn_mfma_f32_16x16x32_bf16(a, b, c, 0, 0, 0);
}

template <bool BIAS, bool OBF16>
__device__ void gemm_tile(const unsigned short* __restrict__ A, const unsigned short* __restrict__ Bt,
                          void* __restrict__ Cv, const float* __restrict__ bias,
                          int M, int Ncols, int ldc, int tm, int tn, SMem& sm)
{
  const int tid = threadIdx.x;
  const int lane = tid & 63;
  const int wm = (tid >> 6) >> 1;
  const int wn = (tid >> 6) & 1;
  const int quad = lane >> 4, l15 = lane & 15;

  const int r0 = tid >> 2, kc = tid & 3;
  int ga0 = tm * 128 + r0;       if (ga0 > M - 1) ga0 = M - 1;
  int ga1 = tm * 128 + 64 + r0;  if (ga1 > M - 1) ga1 = M - 1;
  const int gb0 = tn * 128 + r0;
  const int gb1 = tn * 128 + 64 + r0;
  const unsigned short* gA0 = A + (size_t)ga0 * 512 + kc * 8;
  const unsigned short* gA1 = A + (size_t)ga1 * 512 + kc * 8;
  const unsigned short* gB0 = Bt + (size_t)gb0 * 512 + kc * 8;
  const unsigned short* gB1 = Bt + (size_t)gb1 * 512 + kc * 8;
  const int loff0 = r0 * 32 + kc * 8;
  const int loff1 = (64 + r0) * 32 + kc * 8;

  f32x4 acc[4][4];
  #pragma unroll
  for (int i = 0; i < 4; i++)
    #pragma unroll
    for (int j = 0; j < 4; j++) {
      f32x4 z = {0.f, 0.f, 0.f, 0.f};
      acc[i][j] = z;
    }

  load_lds16(gA0, &sm.g.As[0][loff0]);
  load_lds16(gA1, &sm.g.As[0][loff1]);
  load_lds16(gB0, &sm.g.Bs[0][loff0]);
  load_lds16(gB1, &sm.g.Bs[0][loff1]);
  __syncthreads();

  for (int it = 0; it < 16; ++it) {
    const int cur = it & 1;
    if (it < 15) {
      const int k1 = (it + 1) * 32;
      const int nxt = cur ^ 1;
      load_lds16(gA0 + k1, &sm.g.As[nxt][loff0]);
      load_lds16(gA1 + k1, &sm.g.As[nxt][loff1]);
      load_lds16(gB0 + k1, &sm.g.Bs[nxt][loff0]);
      load_lds16(gB1 + k1, &sm.g.Bs[nxt][loff1]);
    }
    bf16x8 af[4], bfr[4];
    #pragma unroll
    for (int i = 0; i < 4; i++) {
      af[i]  = *(const bf16x8*)&sm.g.As[cur][(wm * 64 + i * 16 + l15) * 32 + quad * 8];
      bfr[i] = *(const bf16x8*)&sm.g.Bs[cur][(wn * 64 + i * 16 + l15) * 32 + quad * 8];
    }
    #pragma unroll
    for (int i = 0; i < 4; i++)
      #pragma unroll
      for (int j = 0; j < 4; j++)
        acc[i][j] = mfma16(af[i], bfr[j], acc[i][j]);
    __syncthreads();
  }

  // epilogue: C/D layout col=lane&15, row=quad*4+reg  [m89-verified]
  #pragma unroll
  for (int i = 0; i < 4; i++) {
    const int row_base = tm * 128 + wm * 64 + i * 16 + quad * 4;
    #pragma unroll
    for (int j = 0; j < 4; j++) {
      const int col = tn * 128 + wn * 64 + j * 16 + l15;
      if (col < Ncols) {
        float badd = BIAS ? bias[col] : 0.f;
        #pragma unroll
        for (int r = 0; r < 4; r++) {
          int row = row_base + r;
          if (row < M) {
            float v = acc[i][j][r] + badd;
            if (OBF16) ((unsigned short*)Cv)[(size_t)row * ldc + col] = f2b(v);
            else       ((float*)Cv)[(size_t)row * ldc + col] = v;
          }
        }
      }
    }
  }
}

// ---- gather: wave-per-node, 8-edge MLP unroll, fused self-loop+bias(+ReLU) ----
__device__ __forceinline__ void acc8(float* a, uint4 v, float nm) {
  a[0] = fmaf(b2f((unsigned short)(v.x & 0xffffu)), nm, a[0]);
  a[1] = fmaf(b2f((unsigned short)(v.x >> 16)),     nm, a[1]);
  a[2] = fmaf(b2f((unsigned short)(v.y & 0xffffu)), nm, a[2]);
  a[3] = fmaf(b2f((unsigned short)(v.y >> 16)),     nm, a[3]);
  a[4] = fmaf(b2f((unsigned short)(v.z & 0xffffu)), nm, a[4]);
  a[5] = fmaf(b2f((unsigned short)(v.z >> 16)),     nm, a[5]);
  a[6] = fmaf(b2f((unsigned short)(v.w & 0xffffu)), nm, a[6]);
  a[7] = fmaf(b2f((unsigned short)(v.w >> 16)),     nm, a[7]);
}

template <bool RELU>
__device__ void gather_phase(const unsigned short* __restrict__ h, const float* __restrict__ dinv,
                             const int* __restrict__ rowstart, const int* __restrict__ csr_src,
                             const float* __restrict__ csr_norm, const float* __restrict__ bias,
                             unsigned short* __restrict__ outb, int n)
{
  const int lane = threadIdx.x & 63;
  const int c8 = lane * 8;
  for (int node = blockIdx.x * 4 + (threadIdx.x >> 6); node < n; node += GW) {
    float di = dinv[node];
    float slf = di * di;
    uint4 hv = *(const uint4*)&h[(size_t)node * 512 + c8];
    const float4* bp = (const float4*)&bias[c8];
    float4 b0 = bp[0], b1 = bp[1];
    float a[8] = {b0.x, b0.y, b0.z, b0.w, b1.x, b1.y, b1.z, b1.w};
    acc8(a, hv, slf);

    const int jb = rowstart[node], je = rowstart[node + 1];
    int j = jb;
    for (; j + 8 <= je; j += 8) {
      int ss[8]; float nrm[8]; uint4 vv[8];
      #pragma unroll
      for (int q = 0; q < 8; q++) { ss[q] = csr_src[j + q]; nrm[q] = csr_norm[j + q]; }
      #pragma unroll
      for (int q = 0; q < 8; q++) vv[q] = *(const uint4*)&h[(size_t)ss[q] * 512 + c8];
      #pragma unroll
      for (int q = 0; q < 8; q++) acc8(a, vv[q], nrm[q]);
    }
    for (; j < je; ++j) {
      uint4 v = *(const uint4*)&h[(size_t)csr_src[j] * 512 + c8];
      acc8(a, v, csr_norm[j]);
    }
    if (RELU) {
      #pragma unroll
      for (int q = 0; q < 8; q++) a[q] = fmaxf(a[q], 0.f);
    }
    uint4 o;
    o.x = (unsigned int)f2b(a[0]) | ((unsigned int)f2b(a[1]) << 16);
    o.y = (unsigned int)f2b(a[2]) | ((unsigned int)f2b(a[3]) << 16);
    o.z = (unsigned int)f2b(a[4]) | ((unsigned int)f2b(a[5]) << 16);
    o.w = (unsigned int)f2b(a[6]) | ((unsigned int)f2b(a[7]) << 16);
    *(uint4*)&outb[(size_t)node * 512 + c8] = o;
  }
}

// ---- LDS-tiled transpose of one 64x64 tile: W fp32 [512][ncols] -> Wt bf16 [.][512] ----
__device__ void wtrans_tile(const float* __restrict__ W, unsigned short* __restrict__ Wt,
                            int ncols, int tr0, int tc0, SMem& sm)
{
  const int t = threadIdx.x;
  const int r = t >> 2, c4 = t & 3;
  #pragma unroll
  for (int i = 0; i < 4; i++) {
    int col = c4 * 16 + i * 4;
    int gc = tc0 + col;
    float4 v;
    if (gc + 3 < ncols) {
      v = *(const float4*)&W[(size_t)(tr0 + r) * ncols + gc];
    } else {
      v.x = (gc + 0 < ncols) ? W[(size_t)(tr0 + r) * ncols + gc + 0] : 0.f;
      v.y = (gc + 1 < ncols) ? W[(size_t)(tr0 + r) * ncols + gc + 1] : 0.f;
      v.z = (gc + 2 < ncols) ? W[(size_t)(tr0 + r) * ncols + gc + 2] : 0.f;
      v.w = (gc + 3 < ncols) ? W[(size_t)(tr0 + r) * ncols + gc + 3] : 0.f;
    }
    sm.tile[r][col] = v.x; sm.tile[r][col + 1] = v.y;
    sm.tile[r][col + 2] = v.z; sm.tile[r][col + 3] = v.w;
  }
  __syncthreads();
  const int o = t >> 2;
  #pragma unroll
  for (int i = 0; i < 4; i++) {
    int k = c4 * 16 + i * 4;
    ushort4 u;
    u.x = f2b(sm.tile[k + 0][o]); u.y = f2b(sm.tile[k + 1][o]);
    u.z = f2b(sm.tile[k + 2][o]); u.w = f2b(sm.tile[k + 3][o]);
    *(ushort4*)&Wt[(size_t)(tc0 + o) * 512 + tr0 + k] = u;
  }
}

// ================= mega-kernel =================
__global__ __launch_bounds__(256, 2)
void gcn_mega(const float* __restrict__ x, const int* __restrict__ src, const int* __restrict__ dst,
              const float* __restrict__ W1, const float* __restrict__ b1,
              const float* __restrict__ W2, const float* __restrict__ b2,
              const float* __restrict__ Wc, const float* __restrict__ bc,
              int* __restrict__ bar, int* __restrict__ edeg, int* __restrict__ rowstart,
              int* __restrict__ csr_src, float* __restrict__ csr_norm, float* __restrict__ dinv,
              unsigned short* __restrict__ xb, unsigned short* __restrict__ W1t,
              unsigned short* __restrict__ W2t, unsigned short* __restrict__ Wct,
              unsigned short* __restrict__ B1, unsigned short* __restrict__ B2,
              float* __restrict__ out, int E)
{
  __shared__ SMem sm;
  const int gt = blockIdx.x * 256 + threadIdx.x;
  const int n = NN;

  // ---- phase 0: x->bf16, weight transposes, in-degree count ----
  {
    const int jobs = blockIdx.x;   // 144 transpose tile-jobs
    if (jobs < 64)       wtrans_tile(W1, W1t, 512, (jobs >> 3) * 64, (jobs & 7) * 64, sm);
    else if (jobs < 128) wtrans_tile(W2, W2t, 512, ((jobs - 64) >> 3) * 64, ((jobs - 64) & 7) * 64, sm);
    else if (jobs < 144) wtrans_tile(Wc, Wct, 100, ((jobs - 128) >> 1) * 64, ((jobs - 128) & 1) * 64, sm);

    const float4* x4 = (const float4*)x;
    ushort4* xb4 = (ushort4*)xb;
    for (int i = gt; i < NN * 128; i += GT) {
      float4 v = x4[i];
      ushort4 u; u.x = f2b(v.x); u.y = f2b(v.y); u.z = f2b(v.z); u.w = f2b(v.w);
      xb4[i] = u;
    }
    for (int e = gt; e < E; e += GT) atomicAdd(&edeg[dst[e]], 1);
  }
  gbar(bar, G * 1);

  // ---- phase 1: scan (block 0 only): rowstart, dinv, edeg->0 (cursor) ----
  if (blockIdx.x == 0) {
    const int t = threadIdx.x;
    const int per = (n + 255) / 256;
    const int lo = t * per;
    const int hi = (lo + per < n) ? lo + per : n;
    int s = 0;
    for (int i = lo; i < hi; i++) s += edeg[i];
    sm.partial[t] = s;
    __syncthreads();
    for (int off = 1; off < 256; off <<= 1) {
      int v = (t >= off) ? sm.partial[t - off] : 0;
      __syncthreads();
      sm.partial[t] += v;
      __syncthreads();
    }
    int run = (t > 0) ? sm.partial[t - 1] : 0;
    for (int i = lo; i < hi; i++) {
      int d = edeg[i];
      rowstart[i] = run; run += d;
      dinv[i] = rsqrtf(1.0f + (float)d);
      edeg[i] = 0;
    }
    if (t == 255) rowstart[n] = run;
  }
  gbar(bar, G * 2);

  // ---- phase 2: CSR fill ----
  for (int e = gt; e < E; e += GT) {
    int s = src[e], d = dst[e];
    int pos = rowstart[d] + atomicAdd(&edeg[d], 1);
    csr_src[pos] = s;
    csr_norm[pos] = dinv[s] * dinv[d];
  }
  gbar(bar, G * 3);

  // ---- phase 3: gemm1: B2 = xb @ W1t^T (bf16 out) ----
  if (blockIdx.x < 79 * 4)
    gemm_tile<false, true>(xb, W1t, B2, nullptr, n, 512, 512, blockIdx.x >> 2, blockIdx.x & 3, sm);
  gbar(bar, G * 4);

  // ---- phase 4: gather1 (+b1, ReLU): B1 = relu(Ahat*B2 + b1) ----
  gather_phase<true>(B2, dinv, rowstart, csr_src, csr_norm, b1, B1, n);
  gbar(bar, G * 5);

  // ---- phase 5: gemm2: B2 = B1 @ W2t^T ----
  if (blockIdx.x < 79 * 4)
    gemm_tile<false, true>(B1, W2t, B2, nullptr, n, 512, 512, blockIdx.x >> 2, blockIdx.x & 3, sm);
  gbar(bar, G * 6);

  // ---- phase 6: gather2 (+b2): B1 = Ahat*B2 + b2 ----
  gather_phase<false>(B2, dinv, rowstart, csr_src, csr_norm, b2, B1, n);
  gbar(bar, G * 7);

  // ---- phase 7: gemm3: out = B1 @ Wct^T + bc (fp32 out) ----
  if (blockIdx.x < 79)
    gemm_tile<true, false>(B1, Wct, out, bc, n, 100, 100, blockIdx.x, 0, sm);
}

extern "C" void kernel_launch(void* const* d_in, const int* in_sizes, int n_in,
                              void* d_out, int out_size, void* d_ws, size_t ws_size,
                              hipStream_t stream) {
  const float* x  = (const float*)d_in[0];
  const int*   ei = (const int*)d_in[1];
  const float* W1 = (const float*)d_in[2];
  const float* b1 = (const float*)d_in[3];
  const float* W2 = (const float*)d_in[4];
  const float* b2 = (const float*)d_in[5];
  const float* Wc = (const float*)d_in[6];
  const float* bc = (const float*)d_in[7];
  float* out = (float*)d_out;

  const int n = NN;
  const int E = in_sizes[1] / 2;
  const int* src = ei;
  const int* dst = ei + E;

  // workspace (~33 MB). bar + edeg contiguous so one memset zeroes both.
  char* w = (char*)d_ws;
  int* bar = (int*)w;                       w += 256;
  int* edeg = (int*)w;                      w += ((n * 4 + 255) / 256) * 256;
  int* rowstart = (int*)w;                  w += (((n + 1) * 4 + 255) / 256) * 256;
  int* csr_src = (int*)w;                   w += ((E * 4 + 255) / 256) * 256;
  float* csr_norm = (float*)w;              w += ((E * 4 + 255) / 256) * 256;
  float* dinv = (float*)w;                  w += ((n * 4 + 255) / 256) * 256;
  unsigned short* xb  = (unsigned short*)w; w += (size_t)n * 512 * 2;
  unsigned short* W1t = (unsigned short*)w; w += 512 * 512 * 2;
  unsigned short* W2t = (unsigned short*)w; w += 512 * 512 * 2;
  unsigned short* Wct = (unsigned short*)w; w += 128 * 512 * 2;
  unsigned short* B1  = (unsigned short*)w; w += (size_t)n * 512 * 2;
  unsigned short* B2  = (unsigned short*)w; w += (size_t)n * 512 * 2;

  hipMemsetAsync(bar, 0, 256 + n * sizeof(int), stream);   // bar + edeg
  gcn_mega<<<G, 256, 0, stream>>>(x, src, dst, W1, b1, W2, b2, Wc, bc,
                                  bar, edeg, rowstart, csr_src, csr_norm, dinv,
                                  xb, W1t, W2t, Wct, B1, B2, out, E);
}

// Round 7
// 197.717 us; speedup vs baseline: 2.9633x; 2.9633x over previous
//
#include <hip/hip_runtime.h>
#include <hip/hip_bf16.h>
#include <stdint.h>

typedef __bf16 bf16_t;
typedef bf16_t bf16x8 __attribute__((ext_vector_type(8)));
typedef float f32x4 __attribute__((ext_vector_type(4)));

#define NN 10000

__device__ __forceinline__ float b2f(unsigned short u) {
  union { unsigned int i; float f; } c; c.i = ((unsigned int)u) << 16; return c.f;
}
__device__ __forceinline__ unsigned short f2b(float f) {
  union { float f; unsigned int i; } c; c.f = f;
  unsigned int x = c.i;
  x += 0x7FFFu + ((x >> 16) & 1u);
  return (unsigned short)(x >> 16);
}
__device__ __forceinline__ uint4 cvt8(float4 a, float4 b) {
  uint4 r;
  r.x = (unsigned int)f2b(a.x) | ((unsigned int)f2b(a.y) << 16);
  r.y = (unsigned int)f2b(a.z) | ((unsigned int)f2b(a.w) << 16);
  r.z = (unsigned int)f2b(b.x) | ((unsigned int)f2b(b.y) << 16);
  r.w = (unsigned int)f2b(b.z) | ((unsigned int)f2b(b.w) << 16);
  return r;
}
__device__ __forceinline__ void load_lds16(const void* g, void* l) {
  __builtin_amdgcn_global_load_lds(
      (const __attribute__((address_space(1))) unsigned int*)g,
      (__attribute__((address_space(3))) unsigned int*)l, 16, 0, 0);
}
__device__ __forceinline__ f32x4 mfma16(bf16x8 a, bf16x8 b, f32x4 c) {
  return __builtin_amdgcn_mfma_f32_16x16x32_bf16(a, b, c, 0, 0, 0);
}

// ---- GEMM tile device fn: C[128x128] @ (tm,tn); A,Bt bf16 [.][512]; dbuf K-loop ----
template <bool OBF16>
__device__ void gemm_tile(const unsigned short* __restrict__ A, const unsigned short* __restrict__ Bt,
                          void* __restrict__ Cv, int M, int Ncols, int ldc, int tm, int tn)
{
  __shared__ __align__(16) unsigned short As[2][128 * 32];
  __shared__ __align__(16) unsigned short Bs[2][128 * 32];
  const int tid = threadIdx.x;
  const int lane = tid & 63;
  const int wm = (tid >> 6) >> 1;
  const int wn = (tid >> 6) & 1;
  const int quad = lane >> 4, l15 = lane & 15;

  const int r0 = tid >> 2, kc = tid & 3;
  int ga0 = tm * 128 + r0;       if (ga0 > M - 1) ga0 = M - 1;
  int ga1 = tm * 128 + 64 + r0;  if (ga1 > M - 1) ga1 = M - 1;
  const int gb0 = tn * 128 + r0;
  const int gb1 = tn * 128 + 64 + r0;
  const unsigned short* gA0 = A + (size_t)ga0 * 512 + kc * 8;
  const unsigned short* gA1 = A + (size_t)ga1 * 512 + kc * 8;
  const unsigned short* gB0 = Bt + (size_t)gb0 * 512 + kc * 8;
  const unsigned short* gB1 = Bt + (size_t)gb1 * 512 + kc * 8;
  const int loff0 = r0 * 32 + kc * 8;
  const int loff1 = (64 + r0) * 32 + kc * 8;

  f32x4 acc[4][4];
  #pragma unroll
  for (int i = 0; i < 4; i++)
    #pragma unroll
    for (int j = 0; j < 4; j++) {
      f32x4 z = {0.f, 0.f, 0.f, 0.f};
      acc[i][j] = z;
    }

  load_lds16(gA0, &As[0][loff0]);
  load_lds16(gA1, &As[0][loff1]);
  load_lds16(gB0, &Bs[0][loff0]);
  load_lds16(gB1, &Bs[0][loff1]);
  __syncthreads();

  for (int it = 0; it < 16; ++it) {
    const int cur = it & 1;
    if (it < 15) {
      const int k1 = (it + 1) * 32;
      const int nxt = cur ^ 1;
      load_lds16(gA0 + k1, &As[nxt][loff0]);
      load_lds16(gA1 + k1, &As[nxt][loff1]);
      load_lds16(gB0 + k1, &Bs[nxt][loff0]);
      load_lds16(gB1 + k1, &Bs[nxt][loff1]);
    }
    bf16x8 af[4], bfr[4];
    #pragma unroll
    for (int i = 0; i < 4; i++) {
      af[i]  = *(const bf16x8*)&As[cur][(wm * 64 + i * 16 + l15) * 32 + quad * 8];
      bfr[i] = *(const bf16x8*)&Bs[cur][(wn * 64 + i * 16 + l15) * 32 + quad * 8];
    }
    #pragma unroll
    for (int i = 0; i < 4; i++)
      #pragma unroll
      for (int j = 0; j < 4; j++)
        acc[i][j] = mfma16(af[i], bfr[j], acc[i][j]);
    __syncthreads();
  }

  // C/D layout col=lane&15, row=quad*4+reg  [m89-verified]
  #pragma unroll
  for (int i = 0; i < 4; i++) {
    const int row_base = tm * 128 + wm * 64 + i * 16 + quad * 4;
    #pragma unroll
    for (int j = 0; j < 4; j++) {
      const int col = tn * 128 + wn * 64 + j * 16 + l15;
      if (col < Ncols) {
        #pragma unroll
        for (int r = 0; r < 4; r++) {
          int row = row_base + r;
          if (row < M) {
            float v = acc[i][j][r];
            if (OBF16) ((unsigned short*)Cv)[(size_t)row * ldc + col] = f2b(v);
            else       ((float*)Cv)[(size_t)row * ldc + col] = v;
          }
        }
      }
    }
  }
}

// ---- LDS-tiled 64x64 transpose: W fp32 [512][ncols] -> Wt bf16 [.][512] ----
__device__ void wtrans_tile(const float* __restrict__ W, unsigned short* __restrict__ Wt,
                            int ncols, int tr0, int tc0)
{
  __shared__ float tile[64][65];
  const int t = threadIdx.x;
  const int r = t >> 2, c4 = t & 3;
  #pragma unroll
  for (int i = 0; i < 4; i++) {
    int col = c4 * 16 + i * 4;
    int gc = tc0 + col;
    float4 v;
    if (gc + 3 < ncols) {
      v = *(const float4*)&W[(size_t)(tr0 + r) * ncols + gc];
    } else {
      v.x = (gc + 0 < ncols) ? W[(size_t)(tr0 + r) * ncols + gc + 0] : 0.f;
      v.y = (gc + 1 < ncols) ? W[(size_t)(tr0 + r) * ncols + gc + 1] : 0.f;
      v.z = (gc + 2 < ncols) ? W[(size_t)(tr0 + r) * ncols + gc + 2] : 0.f;
      v.w = (gc + 3 < ncols) ? W[(size_t)(tr0 + r) * ncols + gc + 3] : 0.f;
    }
    tile[r][col] = v.x; tile[r][col + 1] = v.y;
    tile[r][col + 2] = v.z; tile[r][col + 3] = v.w;
  }
  __syncthreads();
  const int o = t >> 2;
  #pragma unroll
  for (int i = 0; i < 4; i++) {
    int k = c4 * 16 + i * 4;
    ushort4 u;
    u.x = f2b(tile[k + 0][o]); u.y = f2b(tile[k + 1][o]);
    u.z = f2b(tile[k + 2][o]); u.w = f2b(tile[k + 3][o]);
    *(ushort4*)&Wt[(size_t)(tc0 + o) * 512 + tr0 + k] = u;
  }
}

// ================= kernel 1: prep (role-split) =================
// blocks 0..63: W1 transpose tiles; 64..79: Wc transpose tiles;
// 80..511: flat x->bf16, W2->bf16 (no transpose), in-degree count
__global__ __launch_bounds__(256)
void prep(const float* __restrict__ x, const float* __restrict__ W1,
          const float* __restrict__ Wc, const float* __restrict__ W2,
          const int* __restrict__ dst, int* __restrict__ edeg,
          unsigned short* __restrict__ xb, unsigned short* __restrict__ W1t,
          unsigned short* __restrict__ Wct, unsigned short* __restrict__ w2b, int E)
{
  if (blockIdx.x < 64) { wtrans_tile(W1, W1t, 512, (blockIdx.x >> 3) * 64, (blockIdx.x & 7) * 64); return; }
  if (blockIdx.x < 80) { int b = blockIdx.x - 64; wtrans_tile(Wc, Wct, 100, (b >> 1) * 64, (b & 1) * 64); return; }
  const int t0 = (blockIdx.x - 80) * 256 + threadIdx.x;
  const int FT = (512 - 80) * 256;
  const float4* x4 = (const float4*)x;
  ushort4* xb4 = (ushort4*)xb;
  for (int i = t0; i < NN * 128; i += FT) {
    float4 v = x4[i];
    ushort4 u; u.x = f2b(v.x); u.y = f2b(v.y); u.z = f2b(v.z); u.w = f2b(v.w);
    xb4[i] = u;
  }
  const float4* W24 = (const float4*)W2;
  uint4* w2b4 = (uint4*)w2b;
  for (int i = t0; i < 512 * 512 / 8; i += FT)
    w2b4[i] = cvt8(W24[i * 2], W24[i * 2 + 1]);
  for (int e = t0; e < E; e += FT) atomicAdd(&edeg[dst[e]], 1);
}

// ================= kernel 2: scan + W2Wc fold (role-split, grid=6) =================
// block 0: exclusive scan -> rowstart, dinv, edeg->0 (cursor)
// blocks 1..4: W2WcT[j][i] = sum_k Wc[k][j] W2[i][k]  (A=Wct, Bt=w2b)
// block 5: bias2c[j] = b2 @ Wc[:,j] + bc[j]  (0 for j>=100)
__global__ __launch_bounds__(256)
void scan_plus(int* __restrict__ edeg, int* __restrict__ rowstart, float* __restrict__ dinv,
               const unsigned short* __restrict__ Wct, const unsigned short* __restrict__ w2b,
               unsigned short* __restrict__ W2WcT,
               const float* __restrict__ b2, const float* __restrict__ Wc,
               const float* __restrict__ bc, float* __restrict__ bias2c, int n)
{
  if (blockIdx.x == 0) {
    __shared__ int partial[256];
    const int t = threadIdx.x;
    const int per = (n + 255) / 256;
    const int lo = t * per;
    const int hi = (lo + per < n) ? lo + per : n;
    int s = 0;
    for (int i = lo; i < hi; i++) s += edeg[i];
    partial[t] = s;
    __syncthreads();
    for (int off = 1; off < 256; off <<= 1) {
      int v = (t >= off) ? partial[t - off] : 0;
      __syncthreads();
      partial[t] += v;
      __syncthreads();
    }
    int run = (t > 0) ? partial[t - 1] : 0;
    for (int i = lo; i < hi; i++) {
      int d = edeg[i];
      rowstart[i] = run; run += d;
      dinv[i] = rsqrtf(1.0f + (float)d);
      edeg[i] = 0;
    }
    if (t == 255) rowstart[n] = run;
  } else if (blockIdx.x <= 4) {
    gemm_tile<true>(Wct, w2b, W2WcT, 128, 512, 512, 0, blockIdx.x - 1);
  } else {
    const int j = threadIdx.x;
    if (j < 128) {
      float s = 0.f;
      if (j < 100) {
        s = bc[j];
        for (int k = 0; k < 512; k++) s = fmaf(b2[k], Wc[k * 100 + j], s);
      }
      bias2c[j] = s;
    }
  }
}

// ================= kernel 3: gemm1 + CSR fill (role-split) =================
__global__ __launch_bounds__(256)
void fill_gemm1(const unsigned short* __restrict__ xb, const unsigned short* __restrict__ W1t,
                unsigned short* __restrict__ B2,
                const int* __restrict__ src, const int* __restrict__ dst,
                const float* __restrict__ dinv, const int* __restrict__ rowstart,
                int* __restrict__ cursor, int* __restrict__ csr_src,
                float* __restrict__ csr_norm, int E)
{
  if (blockIdx.x < 316) {   // 79 x 4 tiles of 10000x512
    gemm_tile<true>(xb, W1t, B2, NN, 512, 512, blockIdx.x >> 2, blockIdx.x & 3);
  } else {
    int e = (blockIdx.x - 316) * 256 + threadIdx.x;
    const int stride = 157 * 256;
    for (; e < E; e += stride) {
      int s = src[e], d = dst[e];
      int pos = rowstart[d] + atomicAdd(&cursor[d], 1);
      csr_src[pos] = s;
      csr_norm[pos] = dinv[s] * dinv[d];
    }
  }
}

// ================= kernel 4: gather1 (512 cols, +b1, ReLU) =================
__device__ __forceinline__ void acc8(float* a, uint4 v, float nm) {
  a[0] = fmaf(b2f((unsigned short)(v.x & 0xffffu)), nm, a[0]);
  a[1] = fmaf(b2f((unsigned short)(v.x >> 16)),     nm, a[1]);
  a[2] = fmaf(b2f((unsigned short)(v.y & 0xffffu)), nm, a[2]);
  a[3] = fmaf(b2f((unsigned short)(v.y >> 16)),     nm, a[3]);
  a[4] = fmaf(b2f((unsigned short)(v.z & 0xffffu)), nm, a[4]);
  a[5] = fmaf(b2f((unsigned short)(v.z >> 16)),     nm, a[5]);
  a[6] = fmaf(b2f((unsigned short)(v.w & 0xffffu)), nm, a[6]);
  a[7] = fmaf(b2f((unsigned short)(v.w >> 16)),     nm, a[7]);
}

__global__ __launch_bounds__(256)
void gather1(const unsigned short* __restrict__ h, const float* __restrict__ dinv,
             const int* __restrict__ rowstart, const int* __restrict__ csr_src,
             const float* __restrict__ csr_norm, const float* __restrict__ bias,
             unsigned short* __restrict__ outb, int n)
{
  int node = blockIdx.x * 4 + (threadIdx.x >> 6);
  if (node >= n) return;
  const int lane = threadIdx.x & 63;
  const int c8 = lane * 8;

  float di = dinv[node];
  float slf = di * di;
  uint4 hv = *(const uint4*)&h[(size_t)node * 512 + c8];
  const float4* bp = (const float4*)&bias[c8];
  float4 b0 = bp[0], b1 = bp[1];
  float a[8] = {b0.x, b0.y, b0.z, b0.w, b1.x, b1.y, b1.z, b1.w};
  acc8(a, hv, slf);

  const int jb = rowstart[node], je = rowstart[node + 1];
  int j = jb;
  for (; j + 8 <= je; j += 8) {
    int ss[8]; float nrm[8]; uint4 vv[8];
    #pragma unroll
    for (int q = 0; q < 8; q++) { ss[q] = csr_src[j + q]; nrm[q] = csr_norm[j + q]; }
    #pragma unroll
    for (int q = 0; q < 8; q++) vv[q] = *(const uint4*)&h[(size_t)ss[q] * 512 + c8];
    #pragma unroll
    for (int q = 0; q < 8; q++) acc8(a, vv[q], nrm[q]);
  }
  for (; j < je; ++j) {
    uint4 v = *(const uint4*)&h[(size_t)csr_src[j] * 512 + c8];
    acc8(a, v, csr_norm[j]);
  }
  #pragma unroll
  for (int q = 0; q < 8; q++) a[q] = fmaxf(a[q], 0.f);
  uint4 o;
  o.x = (unsigned int)f2b(a[0]) | ((unsigned int)f2b(a[1]) << 16);
  o.y = (unsigned int)f2b(a[2]) | ((unsigned int)f2b(a[3]) << 16);
  o.z = (unsigned int)f2b(a[4]) | ((unsigned int)f2b(a[5]) << 16);
  o.w = (unsigned int)f2b(a[6]) | ((unsigned int)f2b(a[7]) << 16);
  *(uint4*)&outb[(size_t)node * 512 + c8] = o;
}

// ================= kernel 5: gemm2c: C2 = B1 @ W2WcT^T (fp32 out, 128 cols) =================
__global__ __launch_bounds__(256)
void gemm2c(const unsigned short* __restrict__ B1, const unsigned short* __restrict__ W2WcT,
            float* __restrict__ C2)
{
  gemm_tile<false>(B1, W2WcT, C2, NN, 128, 128, blockIdx.x, 0);
}

// ================= kernel 6: gather2c (128 cols fp32) -> out + folded bias =================
__global__ __launch_bounds__(256)
void gather2c(const float* __restrict__ C2, const float* __restrict__ dinv,
              const int* __restrict__ rowstart, const int* __restrict__ csr_src,
              const float* __restrict__ csr_norm, const float* __restrict__ bias2c,
              float* __restrict__ out, int n)
{
  int node = blockIdx.x * 4 + (threadIdx.x >> 6);
  if (node >= n) return;
  const int lane = threadIdx.x & 63;
  const int c2 = lane * 2;

  float di = dinv[node];
  float slf = di * di;
  float2 hv = *(const float2*)&C2[(size_t)node * 128 + c2];
  float a0 = fmaf(hv.x, slf, bias2c[c2]);
  float a1 = fmaf(hv.y, slf, bias2c[c2 + 1]);

  const int jb = rowstart[node], je = rowstart[node + 1];
  int j = jb;
  for (; j + 8 <= je; j += 8) {
    int ss[8]; float nrm[8]; float2 vv[8];
    #pragma unroll
    for (int q = 0; q < 8; q++) { ss[q] = csr_src[j + q]; nrm[q] = csr_norm[j + q]; }
    #pragma unroll
    for (int q = 0; q < 8; q++) vv[q] = *(const float2*)&C2[(size_t)ss[q] * 128 + c2];
    #pragma unroll
    for (int q = 0; q < 8; q++) { a0 = fmaf(vv[q].x, nrm[q], a0); a1 = fmaf(vv[q].y, nrm[q], a1); }
  }
  for (; j < je; ++j) {
    float2 v = *(const float2*)&C2[(size_t)csr_src[j] * 128 + c2];
    float nm = csr_norm[j];
    a0 = fmaf(v.x, nm, a0); a1 = fmaf(v.y, nm, a1);
  }
  if (c2 < 100)   // c2 even => c2+1 <= 99 too
    *(float2*)&out[(size_t)node * 100 + c2] = make_float2(a0, a1);
}

extern "C" void kernel_launch(void* const* d_in, const int* in_sizes, int n_in,
                              void* d_out, int out_size, void* d_ws, size_t ws_size,
                              hipStream_t stream) {
  const float* x  = (const float*)d_in[0];
  const int*   ei = (const int*)d_in[1];
  const float* W1 = (const float*)d_in[2];
  const float* b1 = (const float*)d_in[3];
  const float* W2 = (const float*)d_in[4];
  const float* b2 = (const float*)d_in[5];
  const float* Wc = (const float*)d_in[6];
  const float* bc = (const float*)d_in[7];
  float* out = (float*)d_out;

  const int n = NN;
  const int E = in_sizes[1] / 2;
  const int* src = ei;
  const int* dst = ei + E;

  // workspace (~39 MB)
  char* w = (char*)d_ws;
  int* edeg = (int*)w;                      w += ((n * 4 + 255) / 256) * 256;   // also fill cursor
  int* rowstart = (int*)w;                  w += (((n + 1) * 4 + 255) / 256) * 256;
  int* csr_src = (int*)w;                   w += ((E * 4 + 255) / 256) * 256;
  float* csr_norm = (float*)w;              w += ((E * 4 + 255) / 256) * 256;
  float* dinv = (float*)w;                  w += ((n * 4 + 255) / 256) * 256;
  float* bias2c = (float*)w;                w += 512;
  unsigned short* xb  = (unsigned short*)w; w += (size_t)n * 512 * 2;
  unsigned short* W1t = (unsigned short*)w; w += 512 * 512 * 2;
  unsigned short* Wct = (unsigned short*)w; w += 128 * 512 * 2;
  unsigned short* w2b = (unsigned short*)w; w += 512 * 512 * 2;
  unsigned short* W2WcT = (unsigned short*)w; w += 128 * 512 * 2;
  unsigned short* B1  = (unsigned short*)w; w += (size_t)n * 512 * 2;
  unsigned short* B2  = (unsigned short*)w; w += (size_t)n * 512 * 2;
  float* C2 = (float*)w;                    w += (size_t)n * 128 * 4;

  const int nb_g = (n + 3) / 4;

  hipMemsetAsync(edeg, 0, n * sizeof(int), stream);
  prep<<<512, 256, 0, stream>>>(x, W1, Wc, W2, dst, edeg, xb, W1t, Wct, w2b, E);
  scan_plus<<<6, 256, 0, stream>>>(edeg, rowstart, dinv, Wct, w2b, W2WcT, b2, Wc, bc, bias2c, n);
  fill_gemm1<<<316 + 157, 256, 0, stream>>>(xb, W1t, B2, src, dst, dinv, rowstart,
                                            edeg, csr_src, csr_norm, E);
  gather1<<<nb_g, 256, 0, stream>>>(B2, dinv, rowstart, csr_src, csr_norm, b1, B1, n);
  gemm2c<<<79, 256, 0, stream>>>(B1, W2WcT, C2);
  gather2c<<<nb_g, 256, 0, stream>>>(C2, dinv, rowstart, csr_src, csr_norm, bias2c, out, n);
}